// Round 9
// baseline (317.993 us; speedup 1.0000x reference)
//
#include <hip/hip_runtime.h>

#define N_NODES 50000
#define N_EDGES 800000
#define N_PADROWS 50048   // 782 * 64

#define HIST_BLOCKS 3125   // ceil(800000/256)
#define CONV_BLOCKS 1563   // ceil(50000*8/256)
#define PREP_BLOCKS 160    // ceil(2*20480/256)

typedef unsigned int uint;
typedef unsigned short ushort;

typedef __attribute__((ext_vector_type(8))) short short8;
typedef __attribute__((ext_vector_type(4))) float floatx4;
typedef __attribute__((ext_vector_type(4))) uint uintx4;   // native vec: OK for NT builtins

__device__ __forceinline__ ushort f2bf(float f) {
    uint u = __builtin_bit_cast(uint, f);
    u += 0x7fffu + ((u >> 16) & 1u);      // round-to-nearest-even
    return (ushort)(u >> 16);
}
__device__ __forceinline__ float bf2f(ushort h) {
    uint u = ((uint)h) << 16;
    return __builtin_bit_cast(float, u);
}
__device__ __forceinline__ float bflo(uint w) { return __builtin_bit_cast(float, w << 16); }
__device__ __forceinline__ float bfhi(uint w) { return __builtin_bit_cast(float, w & 0xffff0000u); }
__device__ __forceinline__ uint pack2(float a, float b) {
    return (uint)f2bf(a) | ((uint)f2bf(b) << 16);
}

// ---------------- fused setup: hist + x->bf16 conv + weight swizzle ----------------

__global__ __launch_bounds__(256) void setup_k(const int* __restrict__ ei,
                                               int* __restrict__ counts,
                                               const float* __restrict__ x,
                                               ushort* __restrict__ hb,
                                               const float* __restrict__ basis,
                                               const float* __restrict__ root,
                                               ushort* __restrict__ Bsw) {
    int b = blockIdx.x;
    int tid = threadIdx.x;
    if (b < HIST_BLOCKS) {
        int e = b * 256 + tid;
        if (e < N_EDGES) atomicAdd(&counts[ei[N_EDGES + e]], 1);
    } else if (b < HIST_BLOCKS + CONV_BLOCKS) {
        int i = (b - HIST_BLOCKS) * 256 + tid;
        if (i < N_NODES * 8) {
            const float4* p = (const float4*)(x + (size_t)i * 8);
            float4 a = p[0], bb = p[1];
            uint4 o;
            o.x = pack2(a.x, a.y); o.y = pack2(a.z, a.w);
            o.z = pack2(bb.x, bb.y); o.w = pack2(bb.z, bb.w);
            *(uint4*)(hb + (size_t)i * 8) = o;
        }
    } else {
        int idx = (b - HIST_BLOCKS - CONV_BLOCKS) * 256 + tid;
        if (idx < 2 * 20480) {
            int l = idx / 20480;
            int r = idx % 20480;
            int kb = r >> 11, ct = (r >> 9) & 3, q = (r >> 7) & 3, n = (r >> 3) & 15, j = r & 7;
            int k = kb * 32 + q * 8 + j;
            int c = ct * 16 + n;
            float v = (k < 256) ? basis[(size_t)l * 16384 + k * 64 + c]
                                : root[(size_t)l * 4096 + (k - 256) * 64 + c];
            Bsw[idx] = f2bf(v);
        }
    }
}

// ---------------- scan ----------------

__global__ __launch_bounds__(1024) void scan1_k(const int* __restrict__ counts,
                                                int* __restrict__ start,
                                                int* __restrict__ bsums) {
    __shared__ int s[1024];
    int i = blockIdx.x * 1024 + threadIdx.x;
    int x = (i < N_NODES) ? counts[i] : 0;
    s[threadIdx.x] = x;
    __syncthreads();
    for (int off = 1; off < 1024; off <<= 1) {
        int v = (threadIdx.x >= off) ? s[threadIdx.x - off] : 0;
        __syncthreads();
        s[threadIdx.x] += v;
        __syncthreads();
    }
    if (i < N_NODES) start[i] = s[threadIdx.x] - x;
    if (threadIdx.x == 1023) bsums[blockIdx.x] = s[1023];
}

__global__ void scan2_k(int* __restrict__ bsums, int nblocks) {
    if (threadIdx.x == 0 && blockIdx.x == 0) {
        int run = 0;
        for (int b = 0; b < nblocks; ++b) {
            int t = bsums[b];
            bsums[b] = run;
            run += t;
        }
    }
}

__global__ __launch_bounds__(256) void scan3_k(int* __restrict__ start,
                                               int* __restrict__ cursor,
                                               const int* __restrict__ bsums) {
    int i = blockIdx.x * 256 + threadIdx.x;
    if (i < N_NODES) {
        int v = start[i] + bsums[i >> 10];
        start[i] = v;
        cursor[i] = v;
    }
}

// fused: per edge compute both layers' c = ea @ att, scatter ONE 64B-line record pair (NT)
__global__ __launch_bounds__(256) void scatter_k(const int* __restrict__ ei,
                                                 const float* __restrict__ ea,
                                                 const float* __restrict__ att,   // [2,8,4]
                                                 int* __restrict__ cursor,
                                                 uintx4* __restrict__ rec) {
    int e = blockIdx.x * 256 + threadIdx.x;
    if (e >= N_EDGES) return;
    int src = ei[e];
    int dst = ei[N_EDGES + e];

    const float4* eav = (const float4*)(ea + (size_t)e * 8);
    float4 a0 = eav[0], a1 = eav[1];
    float ev[8] = {a0.x, a0.y, a0.z, a0.w, a1.x, a1.y, a1.z, a1.w};

    float4 c0 = make_float4(0.f, 0.f, 0.f, 0.f);
    float4 c1 = make_float4(0.f, 0.f, 0.f, 0.f);
    const float4* att0 = (const float4*)att;
    const float4* att1 = (const float4*)(att + 32);
    #pragma unroll
    for (int r = 0; r < 8; ++r) {
        float4 w0 = att0[r];
        float4 w1 = att1[r];
        c0.x = fmaf(ev[r], w0.x, c0.x); c0.y = fmaf(ev[r], w0.y, c0.y);
        c0.z = fmaf(ev[r], w0.z, c0.z); c0.w = fmaf(ev[r], w0.w, c0.w);
        c1.x = fmaf(ev[r], w1.x, c1.x); c1.y = fmaf(ev[r], w1.y, c1.y);
        c1.z = fmaf(ev[r], w1.z, c1.z); c1.w = fmaf(ev[r], w1.w, c1.w);
    }
    int pos = atomicAdd(&cursor[dst], 1);
    uintx4 r0 = {(uint)src, pack2(c0.x, c0.y), pack2(c0.z, c0.w), 0u};
    uintx4 r1 = {(uint)src, pack2(c1.x, c1.y), pack2(c1.z, c1.w), 0u};
    __builtin_nontemporal_store(r0, &rec[2 * (size_t)pos]);
    __builtin_nontemporal_store(r1, &rec[2 * (size_t)pos + 1]);
}

// ---------------- per-layer kernels ----------------

// one wave per dst node; lane = channel. recs = rec (+1 for layer 1), stride 2 uintx4/edge.
// NT on the rec stream + y16 stream to keep hb (6.4MB) resident in L2.
__global__ __launch_bounds__(256) void agg_k(const int* __restrict__ start,
                                             const int* __restrict__ counts,
                                             const uintx4* __restrict__ recs,
                                             const ushort* __restrict__ hb,
                                             ushort* __restrict__ y16) {
    int node = blockIdx.x * 4 + (threadIdx.x >> 6);
    int lane = threadIdx.x & 63;
    if (node >= N_NODES) return;
    int s = start[node];
    int cnt = counts[node];

    float y0 = 0.f, y1 = 0.f, y2 = 0.f, y3 = 0.f;
    int j = 0;
    for (; j + 7 < cnt; j += 8) {
        uintx4 r[8];
        #pragma unroll
        for (int i = 0; i < 8; ++i) r[i] = __builtin_nontemporal_load(&recs[2 * (size_t)(s + j + i)]);
        float hv[8];
        #pragma unroll
        for (int i = 0; i < 8; ++i) hv[i] = bf2f(hb[(size_t)r[i].x * 64 + lane]);
        #pragma unroll
        for (int i = 0; i < 8; ++i) {
            y0 = fmaf(bflo(r[i].y), hv[i], y0);
            y1 = fmaf(bfhi(r[i].y), hv[i], y1);
            y2 = fmaf(bflo(r[i].z), hv[i], y2);
            y3 = fmaf(bfhi(r[i].z), hv[i], y3);
        }
    }
    for (; j + 1 < cnt; j += 2) {
        uintx4 ra = __builtin_nontemporal_load(&recs[2 * (size_t)(s + j)]);
        uintx4 rb = __builtin_nontemporal_load(&recs[2 * (size_t)(s + j + 1)]);
        float ha = bf2f(hb[(size_t)ra.x * 64 + lane]);
        float hbv = bf2f(hb[(size_t)rb.x * 64 + lane]);
        y0 = fmaf(bflo(ra.y), ha, y0); y1 = fmaf(bfhi(ra.y), ha, y1);
        y2 = fmaf(bflo(ra.z), ha, y2); y3 = fmaf(bfhi(ra.z), ha, y3);
        y0 = fmaf(bflo(rb.y), hbv, y0); y1 = fmaf(bfhi(rb.y), hbv, y1);
        y2 = fmaf(bflo(rb.z), hbv, y2); y3 = fmaf(bfhi(rb.z), hbv, y3);
    }
    if (j < cnt) {
        uintx4 r = __builtin_nontemporal_load(&recs[2 * (size_t)(s + j)]);
        float hv = bf2f(hb[(size_t)r.x * 64 + lane]);
        y0 = fmaf(bflo(r.y), hv, y0); y1 = fmaf(bfhi(r.y), hv, y1);
        y2 = fmaf(bflo(r.z), hv, y2); y3 = fmaf(bfhi(r.z), hv, y3);
    }
    ushort* yr = y16 + (size_t)node * 256;
    __builtin_nontemporal_store(f2bf(y0), yr + lane);
    __builtin_nontemporal_store(f2bf(y1), yr + 64 + lane);
    __builtin_nontemporal_store(f2bf(y2), yr + 128 + lane);
    __builtin_nontemporal_store(f2bf(y3), yr + 192 + lane);
}

// MFMA GEMM: out[n][c] = sum_{k<320} [y16|hb][n][k] * W[k][c] + bias[c]
__global__ __launch_bounds__(256) void gemm_k(const ushort* __restrict__ y16,   // [N_PADROWS][256] bf16
                                              const ushort* __restrict__ hb,    // [N_PADROWS][64] bf16
                                              const ushort* __restrict__ Bsw,   // [2560][8] bf16 fragment order
                                              const float* __restrict__ bias,   // [64]
                                              float* __restrict__ outf,         // fp32 out or null
                                              ushort* __restrict__ outh,        // next hb (bf16) or null
                                              int relu) {
    __shared__ uintx4 bs[2560];   // 40 KB
    const int tid = threadIdx.x;
    for (int i = tid; i < 2560; i += 256) bs[i] = ((const uintx4*)Bsw)[i];

    const int lane = tid & 63;
    const int wid = tid >> 6;
    const int nlo = lane & 15;
    const int quad = lane >> 4;
    const int m0 = blockIdx.x * 64 + wid * 16;

    floatx4 acc[4];
    #pragma unroll
    for (int ct = 0; ct < 4; ++ct) acc[ct] = (floatx4){0.f, 0.f, 0.f, 0.f};

    const ushort* yrow = y16 + (size_t)(m0 + nlo) * 256 + quad * 8;
    const ushort* hrow = hb  + (size_t)(m0 + nlo) * 64  + quad * 8;
    __syncthreads();

    #pragma unroll
    for (int kb = 0; kb < 10; ++kb) {
        uintx4 av = (kb < 8) ? __builtin_nontemporal_load((const uintx4*)(yrow + kb * 32))
                             : *(const uintx4*)(hrow + (kb - 8) * 32);
        short8 a = __builtin_bit_cast(short8, av);
        #pragma unroll
        for (int ct = 0; ct < 4; ++ct) {
            short8 b = __builtin_bit_cast(short8, bs[(kb * 4 + ct) * 64 + lane]);
            acc[ct] = __builtin_amdgcn_mfma_f32_16x16x32_bf16(a, b, acc[ct], 0, 0, 0);
        }
    }

    // C/D layout: col = ct*16 + (lane&15), row = quad*4 + reg
    #pragma unroll
    for (int ct = 0; ct < 4; ++ct) {
        int col = ct * 16 + nlo;
        float bv = bias[col];
        #pragma unroll
        for (int r = 0; r < 4; ++r) {
            int row = m0 + quad * 4 + r;
            if (row < N_NODES) {
                float v = acc[ct][r] + bv;
                if (relu) v = fmaxf(v, 0.f);
                if (outf) outf[(size_t)row * 64 + col] = v;
                if (outh) outh[(size_t)row * 64 + col] = f2bf(v);
            }
        }
    }
}

// ---------------- launch ----------------

extern "C" void kernel_launch(void* const* d_in, const int* in_sizes, int n_in,
                              void* d_out, int out_size, void* d_ws, size_t ws_size,
                              hipStream_t stream) {
    const float* x     = (const float*)d_in[0];
    const int*   ei    = (const int*)d_in[1];
    const float* ea    = (const float*)d_in[2];
    const float* basis = (const float*)d_in[3];  // [2,4,64,64]
    const float* att   = (const float*)d_in[4];  // [2,8,4]
    const float* root  = (const float*)d_in[5];  // [2,64,64]
    const float* bias  = (const float*)d_in[6];  // [2,64]
    float* out = (float*)d_out;

    char* p = (char*)d_ws;
    uintx4* rec    = (uintx4*)p;  p += (size_t)N_EDGES * 32;          // 25.6 MB
    ushort* y16    = (ushort*)p;  p += (size_t)N_PADROWS * 256 * 2;   // 25.6 MB
    ushort* hb0    = (ushort*)p;  p += (size_t)N_PADROWS * 64 * 2;    //  6.4 MB (x bf16)
    ushort* hb1    = (ushort*)p;  p += (size_t)N_PADROWS * 64 * 2;    //  6.4 MB (h1 bf16)
    ushort* Bsw    = (ushort*)p;  p += (size_t)2 * 20480 * 2;         //  80 KB
    int*    counts = (int*)p;     p += (size_t)N_NODES * 4;
    int*    start  = (int*)p;     p += (size_t)N_NODES * 4;
    int*    cursor = (int*)p;     p += (size_t)N_NODES * 4;
    int*    bsums  = (int*)p;     p += 64 * 4;

    const int scan_blocks = (N_NODES + 1023) / 1024;  // 49

    (void)hipMemsetAsync(counts, 0, (size_t)N_NODES * 4, stream);
    setup_k<<<HIST_BLOCKS + CONV_BLOCKS + PREP_BLOCKS, 256, 0, stream>>>(
        ei, counts, x, hb0, basis, root, Bsw);
    scan1_k<<<scan_blocks, 1024, 0, stream>>>(counts, start, bsums);
    scan2_k<<<1, 64, 0, stream>>>(bsums, scan_blocks);
    scan3_k<<<(N_NODES + 255) / 256, 256, 0, stream>>>(start, cursor, bsums);
    scatter_k<<<(N_EDGES + 255) / 256, 256, 0, stream>>>(ei, ea, att, cursor, rec);

    dim3 agg_grid((N_NODES + 3) / 4);
    dim3 gemm_grid(N_PADROWS / 64);   // 782

    // ---- layer 0: h = x (hb0) -> h1 bf16 (hb1) ----
    agg_k<<<agg_grid, 256, 0, stream>>>(start, counts, rec, hb0, y16);
    gemm_k<<<gemm_grid, 256, 0, stream>>>(y16, hb0, Bsw, bias, (float*)0, hb1, 1);

    // ---- layer 1: h = h1 (hb1) -> out fp32 ----
    agg_k<<<agg_grid, 256, 0, stream>>>(start, counts, rec + 1, hb1, y16);
    gemm_k<<<gemm_grid, 256, 0, stream>>>(y16, hb1, Bsw + 20480, bias + 64, out, (ushort*)0, 0);
}

// Round 10
// 279.685 us; speedup vs baseline: 1.1370x; 1.1370x over previous
//
#include <hip/hip_runtime.h>

#define N_NODES 50000
#define N_EDGES 800000

#define HIST_BLOCKS 3125   // ceil(800000/256)
#define CONV_BLOCKS 1563   // ceil(50000*8/256)
#define PREP_BLOCKS 160    // ceil(2*20480/256)

typedef unsigned int uint;
typedef unsigned short ushort;

typedef __attribute__((ext_vector_type(8))) short short8;
typedef __attribute__((ext_vector_type(4))) float floatx4;
typedef __attribute__((ext_vector_type(4))) uint uintx4;

__device__ __forceinline__ ushort f2bf(float f) {
    uint u = __builtin_bit_cast(uint, f);
    u += 0x7fffu + ((u >> 16) & 1u);      // round-to-nearest-even
    return (ushort)(u >> 16);
}
__device__ __forceinline__ float bf2f(ushort h) {
    uint u = ((uint)h) << 16;
    return __builtin_bit_cast(float, u);
}
__device__ __forceinline__ float bflo(uint w) { return __builtin_bit_cast(float, w << 16); }
__device__ __forceinline__ float bfhi(uint w) { return __builtin_bit_cast(float, w & 0xffff0000u); }
__device__ __forceinline__ uint pack2(float a, float b) {
    return (uint)f2bf(a) | ((uint)f2bf(b) << 16);
}

// ---------------- fused setup: hist + x->bf16 conv + weight swizzle ----------------

__global__ __launch_bounds__(256) void setup_k(const int* __restrict__ ei,
                                               int* __restrict__ counts,
                                               const float* __restrict__ x,
                                               ushort* __restrict__ hb,
                                               const float* __restrict__ basis,
                                               const float* __restrict__ root,
                                               ushort* __restrict__ Bsw) {
    int b = blockIdx.x;
    int tid = threadIdx.x;
    if (b < HIST_BLOCKS) {
        int e = b * 256 + tid;
        if (e < N_EDGES) atomicAdd(&counts[ei[N_EDGES + e]], 1);
    } else if (b < HIST_BLOCKS + CONV_BLOCKS) {
        int i = (b - HIST_BLOCKS) * 256 + tid;
        if (i < N_NODES * 8) {
            const float4* p = (const float4*)(x + (size_t)i * 8);
            float4 a = p[0], bb = p[1];
            uint4 o;
            o.x = pack2(a.x, a.y); o.y = pack2(a.z, a.w);
            o.z = pack2(bb.x, bb.y); o.w = pack2(bb.z, bb.w);
            *(uint4*)(hb + (size_t)i * 8) = o;
        }
    } else {
        int idx = (b - HIST_BLOCKS - CONV_BLOCKS) * 256 + tid;
        if (idx < 2 * 20480) {
            int l = idx / 20480;
            int r = idx % 20480;
            int kb = r >> 11, ct = (r >> 9) & 3, q = (r >> 7) & 3, n = (r >> 3) & 15, j = r & 7;
            int k = kb * 32 + q * 8 + j;
            int c = ct * 16 + n;
            float v = (k < 256) ? basis[(size_t)l * 16384 + k * 64 + c]
                                : root[(size_t)l * 4096 + (k - 256) * 64 + c];
            Bsw[idx] = f2bf(v);
        }
    }
}

// ---------------- scan ----------------

__global__ __launch_bounds__(1024) void scan1_k(const int* __restrict__ counts,
                                                int* __restrict__ start,
                                                int* __restrict__ bsums) {
    __shared__ int s[1024];
    int i = blockIdx.x * 1024 + threadIdx.x;
    int x = (i < N_NODES) ? counts[i] : 0;
    s[threadIdx.x] = x;
    __syncthreads();
    for (int off = 1; off < 1024; off <<= 1) {
        int v = (threadIdx.x >= off) ? s[threadIdx.x - off] : 0;
        __syncthreads();
        s[threadIdx.x] += v;
        __syncthreads();
    }
    if (i < N_NODES) start[i] = s[threadIdx.x] - x;
    if (threadIdx.x == 1023) bsums[blockIdx.x] = s[1023];
}

__global__ void scan2_k(int* __restrict__ bsums, int nblocks) {
    if (threadIdx.x == 0 && blockIdx.x == 0) {
        int run = 0;
        for (int b = 0; b < nblocks; ++b) {
            int t = bsums[b];
            bsums[b] = run;
            run += t;
        }
    }
}

__global__ __launch_bounds__(256) void scan3_k(int* __restrict__ start,
                                               int* __restrict__ cursor,
                                               const int* __restrict__ bsums) {
    int i = blockIdx.x * 256 + threadIdx.x;
    if (i < N_NODES) {
        int v = start[i] + bsums[i >> 10];
        start[i] = v;
        cursor[i] = v;
    }
}

// fused: per edge compute both layers' c = ea @ att, scatter ONE 64B-line record pair
// (plain stores: L2 write-combining merges the two 16B halves; NT made it worse — round 9)
__global__ __launch_bounds__(256) void scatter_k(const int* __restrict__ ei,
                                                 const float* __restrict__ ea,
                                                 const float* __restrict__ att,   // [2,8,4]
                                                 int* __restrict__ cursor,
                                                 uintx4* __restrict__ rec) {
    int e = blockIdx.x * 256 + threadIdx.x;
    if (e >= N_EDGES) return;
    int src = ei[e];
    int dst = ei[N_EDGES + e];

    const float4* eav = (const float4*)(ea + (size_t)e * 8);
    float4 a0 = eav[0], a1 = eav[1];
    float ev[8] = {a0.x, a0.y, a0.z, a0.w, a1.x, a1.y, a1.z, a1.w};

    float4 c0 = make_float4(0.f, 0.f, 0.f, 0.f);
    float4 c1 = make_float4(0.f, 0.f, 0.f, 0.f);
    const float4* att0 = (const float4*)att;
    const float4* att1 = (const float4*)(att + 32);
    #pragma unroll
    for (int r = 0; r < 8; ++r) {
        float4 w0 = att0[r];
        float4 w1 = att1[r];
        c0.x = fmaf(ev[r], w0.x, c0.x); c0.y = fmaf(ev[r], w0.y, c0.y);
        c0.z = fmaf(ev[r], w0.z, c0.z); c0.w = fmaf(ev[r], w0.w, c0.w);
        c1.x = fmaf(ev[r], w1.x, c1.x); c1.y = fmaf(ev[r], w1.y, c1.y);
        c1.z = fmaf(ev[r], w1.z, c1.z); c1.w = fmaf(ev[r], w1.w, c1.w);
    }
    int pos = atomicAdd(&cursor[dst], 1);
    uintx4 r0 = {(uint)src, pack2(c0.x, c0.y), pack2(c0.z, c0.w), 0u};
    uintx4 r1 = {(uint)src, pack2(c1.x, c1.y), pack2(c1.z, c1.w), 0u};
    rec[2 * (size_t)pos]     = r0;
    rec[2 * (size_t)pos + 1] = r1;
}

// ---------------- fused per-layer kernel: aggregate + MFMA GEMM ----------------
// Block = 16 nodes (exactly; 50000/16 = 3125 blocks). Phase 1: wave w aggregates
// nodes m0+4w..m0+4w+3 into LDS ys (bf16, padded rows). Phase 2: wave w computes
// col-tile w of out[16x64] via 10 MFMAs (K=320: ys | hb rows), B-frags from L2.
__global__ __launch_bounds__(256) void aggmm_k(const int* __restrict__ start,
                                               const int* __restrict__ counts,
                                               const uintx4* __restrict__ recs,   // rec (+1 for layer 1)
                                               const ushort* __restrict__ hb,     // [N][64] bf16
                                               const ushort* __restrict__ Bsw,    // [2560][8] bf16 frag order
                                               const float* __restrict__ bias,    // [64]
                                               float* __restrict__ outf,          // fp32 out or null
                                               ushort* __restrict__ outh,         // next hb or null
                                               int relu) {
    __shared__ ushort ys[16][264];   // 16 rows x 256 + 8 pad (528B stride: 2-way bank alias = free)

    const int tid = threadIdx.x;
    const int lane = tid & 63;
    const int wid = tid >> 6;
    const int m0 = blockIdx.x * 16;

    // ---- phase 1: aggregation ----
    for (int t = 0; t < 4; ++t) {
        int node = m0 + wid * 4 + t;
        int s = start[node];
        int cnt = counts[node];

        float y0 = 0.f, y1 = 0.f, y2 = 0.f, y3 = 0.f;
        int j = 0;
        for (; j + 7 < cnt; j += 8) {
            uintx4 r[8];
            #pragma unroll
            for (int i = 0; i < 8; ++i) r[i] = recs[2 * (size_t)(s + j + i)];
            float hv[8];
            #pragma unroll
            for (int i = 0; i < 8; ++i) hv[i] = bf2f(hb[(size_t)r[i].x * 64 + lane]);
            #pragma unroll
            for (int i = 0; i < 8; ++i) {
                y0 = fmaf(bflo(r[i].y), hv[i], y0);
                y1 = fmaf(bfhi(r[i].y), hv[i], y1);
                y2 = fmaf(bflo(r[i].z), hv[i], y2);
                y3 = fmaf(bfhi(r[i].z), hv[i], y3);
            }
        }
        for (; j + 1 < cnt; j += 2) {
            uintx4 ra = recs[2 * (size_t)(s + j)];
            uintx4 rb = recs[2 * (size_t)(s + j + 1)];
            float ha = bf2f(hb[(size_t)ra.x * 64 + lane]);
            float hbv = bf2f(hb[(size_t)rb.x * 64 + lane]);
            y0 = fmaf(bflo(ra.y), ha, y0); y1 = fmaf(bfhi(ra.y), ha, y1);
            y2 = fmaf(bflo(ra.z), ha, y2); y3 = fmaf(bfhi(ra.z), ha, y3);
            y0 = fmaf(bflo(rb.y), hbv, y0); y1 = fmaf(bfhi(rb.y), hbv, y1);
            y2 = fmaf(bflo(rb.z), hbv, y2); y3 = fmaf(bfhi(rb.z), hbv, y3);
        }
        if (j < cnt) {
            uintx4 r = recs[2 * (size_t)(s + j)];
            float hv = bf2f(hb[(size_t)r.x * 64 + lane]);
            y0 = fmaf(bflo(r.y), hv, y0); y1 = fmaf(bfhi(r.y), hv, y1);
            y2 = fmaf(bflo(r.z), hv, y2); y3 = fmaf(bfhi(r.z), hv, y3);
        }
        int lr = wid * 4 + t;
        ys[lr][lane]       = f2bf(y0);
        ys[lr][64 + lane]  = f2bf(y1);
        ys[lr][128 + lane] = f2bf(y2);
        ys[lr][192 + lane] = f2bf(y3);
    }
    __syncthreads();

    // ---- phase 2: 16x64 GEMM, wave wid = col-tile wid ----
    const int nlo = lane & 15;
    const int quad = lane >> 4;

    floatx4 acc = (floatx4){0.f, 0.f, 0.f, 0.f};
    const ushort* hrow = hb + (size_t)(m0 + nlo) * 64 + quad * 8;
    const uintx4* bptr = (const uintx4*)Bsw;

    #pragma unroll
    for (int kb = 0; kb < 10; ++kb) {
        short8 a;
        if (kb < 8) a = *(const short8*)&ys[nlo][quad * 8 + kb * 32];
        else        a = __builtin_bit_cast(short8, *(const uintx4*)(hrow + (kb - 8) * 32));
        short8 b = __builtin_bit_cast(short8, bptr[(kb * 4 + wid) * 64 + lane]);
        acc = __builtin_amdgcn_mfma_f32_16x16x32_bf16(a, b, acc, 0, 0, 0);
    }

    // C/D layout: col = wid*16 + (lane&15), row = quad*4 + reg
    int col = wid * 16 + nlo;
    float bv = bias[col];
    #pragma unroll
    for (int r = 0; r < 4; ++r) {
        int row = m0 + quad * 4 + r;
        float v = acc[r] + bv;
        if (relu) v = fmaxf(v, 0.f);
        if (outf) outf[(size_t)row * 64 + col] = v;
        if (outh) outh[(size_t)row * 64 + col] = f2bf(v);
    }
}

// ---------------- launch ----------------

extern "C" void kernel_launch(void* const* d_in, const int* in_sizes, int n_in,
                              void* d_out, int out_size, void* d_ws, size_t ws_size,
                              hipStream_t stream) {
    const float* x     = (const float*)d_in[0];
    const int*   ei    = (const int*)d_in[1];
    const float* ea    = (const float*)d_in[2];
    const float* basis = (const float*)d_in[3];  // [2,4,64,64]
    const float* att   = (const float*)d_in[4];  // [2,8,4]
    const float* root  = (const float*)d_in[5];  // [2,64,64]
    const float* bias  = (const float*)d_in[6];  // [2,64]
    float* out = (float*)d_out;

    char* p = (char*)d_ws;
    uintx4* rec    = (uintx4*)p;  p += (size_t)N_EDGES * 32;        // 25.6 MB
    ushort* hb0    = (ushort*)p;  p += (size_t)N_NODES * 64 * 2;    //  6.4 MB (x bf16)
    ushort* hb1    = (ushort*)p;  p += (size_t)N_NODES * 64 * 2;    //  6.4 MB (h1 bf16)
    ushort* Bsw    = (ushort*)p;  p += (size_t)2 * 20480 * 2;       //  80 KB
    int*    counts = (int*)p;     p += (size_t)N_NODES * 4;
    int*    start  = (int*)p;     p += (size_t)N_NODES * 4;
    int*    cursor = (int*)p;     p += (size_t)N_NODES * 4;
    int*    bsums  = (int*)p;     p += 64 * 4;

    const int scan_blocks = (N_NODES + 1023) / 1024;  // 49

    (void)hipMemsetAsync(counts, 0, (size_t)N_NODES * 4, stream);
    setup_k<<<HIST_BLOCKS + CONV_BLOCKS + PREP_BLOCKS, 256, 0, stream>>>(
        ei, counts, x, hb0, basis, root, Bsw);
    scan1_k<<<scan_blocks, 1024, 0, stream>>>(counts, start, bsums);
    scan2_k<<<1, 64, 0, stream>>>(bsums, scan_blocks);
    scan3_k<<<(N_NODES + 255) / 256, 256, 0, stream>>>(start, cursor, bsums);
    scatter_k<<<(N_EDGES + 255) / 256, 256, 0, stream>>>(ei, ea, att, cursor, rec);

    dim3 fuse_grid(N_NODES / 16);   // 3125

    // ---- layer 0: h = x (hb0) -> h1 bf16 (hb1) ----
    aggmm_k<<<fuse_grid, 256, 0, stream>>>(start, counts, rec, hb0, Bsw, bias,
                                           (float*)0, hb1, 1);
    // ---- layer 1: h = h1 (hb1) -> out fp32 ----
    aggmm_k<<<fuse_grid, 256, 0, stream>>>(start, counts, rec + 1, hb1, Bsw + 20480, bias + 64,
                                           out, (ushort*)0, 0);
}